// Round 16
// baseline (440.557 us; speedup 1.0000x reference)
//
#include <hip/hip_runtime.h>

#define NN 100000
#define NE 1600000
#define NBUCK 782   // ceil(NN/128) target buckets of 128 nodes
// IN_FEAT=128, N_HEADS=8, OUT_FEAT=16, H*F=128

static __device__ __forceinline__ unsigned short f32_to_bf16_rne(float x) {
    unsigned int u = __float_as_uint(x);
    u += 0x7fff + ((u >> 16) & 1);   // round-to-nearest-even
    return (unsigned short)(u >> 16);
}
static __device__ __forceinline__ float bf16_to_f32(unsigned int bits16) {
    return __uint_as_float(bits16 << 16);
}

// ---------------- Kernel 1: fused proj-GEMM + attention scores (round-13-measured) ----------------
__global__ __launch_bounds__(256) void gemm_score_kernel(const float* __restrict__ x,
                                                         const float* __restrict__ W,
                                                         const float* __restrict__ a_src,
                                                         const float* __restrict__ a_tgt,
                                                         unsigned short* __restrict__ projT,
                                                         unsigned short* __restrict__ s_src_b,
                                                         unsigned short* __restrict__ s_tgt_b) {
    __shared__ float sXT[32][68];   // k-major, padded
    __shared__ float sW[32][128];
    const int t = threadIdx.x;
    const int n0 = blockIdx.x * 64;
    const int c0 = (t & 31) * 4;    // head h=c0>>4, first feat f0=c0&15
    const int r0 = t >> 5;          // row group 0..7
    float acc[8][4];
#pragma unroll
    for (int i = 0; i < 8; i++)
#pragma unroll
        for (int j = 0; j < 4; j++) acc[i][j] = 0.f;

    for (int kt = 0; kt < 128; kt += 32) {
#pragma unroll
        for (int p = 0; p < 2; p++) {
            int idx = t + p * 256;
            int r = idx >> 3;
            int kk = idx & 7;
            float4 v = make_float4(0.f, 0.f, 0.f, 0.f);
            int n = n0 + r;
            if (n < NN) v = *reinterpret_cast<const float4*>(&x[(size_t)n * 128 + kt + kk * 4]);
            sXT[kk * 4 + 0][r] = v.x;
            sXT[kk * 4 + 1][r] = v.y;
            sXT[kk * 4 + 2][r] = v.z;
            sXT[kk * 4 + 3][r] = v.w;
        }
#pragma unroll
        for (int p = 0; p < 4; p++) {
            int idx = t + p * 256;
            int kr = idx >> 5;
            int c4 = idx & 31;
            float4 v = *reinterpret_cast<const float4*>(&W[(size_t)(kt + kr) * 128 + c4 * 4]);
            *reinterpret_cast<float4*>(&sW[kr][c4 * 4]) = v;
        }
        __syncthreads();
#pragma unroll
        for (int k = 0; k < 32; k++) {
            float4 xa = *reinterpret_cast<const float4*>(&sXT[k][r0 * 8]);
            float4 xb = *reinterpret_cast<const float4*>(&sXT[k][r0 * 8 + 4]);
            float4 wv = *reinterpret_cast<const float4*>(&sW[k][c0]);
            float xs[8] = {xa.x, xa.y, xa.z, xa.w, xb.x, xb.y, xb.z, xb.w};
#pragma unroll
            for (int i = 0; i < 8; i++) {
                acc[i][0] += xs[i] * wv.x;
                acc[i][1] += xs[i] * wv.y;
                acc[i][2] += xs[i] * wv.z;
                acc[i][3] += xs[i] * wv.w;
            }
        }
        __syncthreads();
    }
    const int h  = c0 >> 4;
    const int f0 = c0 & 15;
    const float aS0 = a_src[c0], aS1 = a_src[c0 + 1], aS2 = a_src[c0 + 2], aS3 = a_src[c0 + 3];
    const float aT0 = a_tgt[c0], aT1 = a_tgt[c0 + 1], aT2 = a_tgt[c0 + 2], aT3 = a_tgt[c0 + 3];
#pragma unroll
    for (int i = 0; i < 8; i++) {
        int n = n0 + r0 * 8 + i;
        if (n < NN) {
            unsigned short* pT = &projT[(size_t)n * 128];
#pragma unroll
            for (int j = 0; j < 4; j++) pT[(f0 + j) * 8 + h] = f32_to_bf16_rne(acc[i][j]);
            float ss = acc[i][0] * aS0 + acc[i][1] * aS1 + acc[i][2] * aS2 + acc[i][3] * aS3;
            float st = acc[i][0] * aT0 + acc[i][1] * aT1 + acc[i][2] * aT2 + acc[i][3] * aT3;
            ss += __shfl_xor(ss, 1);
            ss += __shfl_xor(ss, 2);
            st += __shfl_xor(st, 1);
            st += __shfl_xor(st, 2);
            if ((t & 3) == 0) {
                s_src_b[(size_t)n * 8 + h] = f32_to_bf16_rne(ss);
                s_tgt_b[(size_t)n * 8 + h] = f32_to_bf16_rne(st);
            }
        }
    }
}

// ---------------- Bucket counting-sort (782 buckets of 128 target nodes) ----------------
__global__ __launch_bounds__(256) void bucket_hist_kernel(const int* __restrict__ tgt,
                                                          int* __restrict__ counts) {
    __shared__ int bins[NBUCK];
    for (int i = threadIdx.x; i < NBUCK; i += 256) bins[i] = 0;
    __syncthreads();
    int base = blockIdx.x * 2048;
#pragma unroll
    for (int i = 0; i < 8; i++) {
        int e = base + i * 256 + threadIdx.x;
        if (e < NE) atomicAdd(&bins[tgt[e] >> 7], 1);
    }
    __syncthreads();
    for (int i = threadIdx.x; i < NBUCK; i += 256)
        if (bins[i]) atomicAdd(&counts[i], bins[i]);
}

__global__ __launch_bounds__(1024) void bucket_scan_kernel(const int* __restrict__ counts,
                                                           int* __restrict__ base,
                                                           int* __restrict__ gcursor) {
    __shared__ int sc[1024];
    int t = threadIdx.x;
    int v = (t < NBUCK) ? counts[t] : 0;
    sc[t] = v;
    __syncthreads();
    for (int off = 1; off < 1024; off <<= 1) {
        int u = (t >= off) ? sc[t - off] : 0;
        __syncthreads();
        sc[t] += u;
        __syncthreads();
    }
    if (t < NBUCK) {
        int ex = sc[t] - v;
        base[t] = ex;
        gcursor[t] = ex;
    }
    if (t == NBUCK - 1) base[NBUCK] = sc[t];   // == NE
}

// payload: (src<<7) | (tgt&127)  — src < 2^17, fits in 24 bits
__global__ __launch_bounds__(256) void bucket_scatter_kernel(const int* __restrict__ src,
                                                             const int* __restrict__ tgt,
                                                             int* __restrict__ gcursor,
                                                             int* __restrict__ sorted) {
    __shared__ int bins[NBUCK];
    __shared__ int basel[NBUCK];
    for (int i = threadIdx.x; i < NBUCK; i += 256) bins[i] = 0;
    __syncthreads();
    int blk = blockIdx.x * 2048;
    int myb[8], myr[8], myp[8];
#pragma unroll
    for (int i = 0; i < 8; i++) {
        int e = blk + i * 256 + threadIdx.x;
        if (e < NE) {
            int tg = tgt[e];
            int b = tg >> 7;
            myb[i] = b;
            myr[i] = atomicAdd(&bins[b], 1);
            myp[i] = (src[e] << 7) | (tg & 127);
        } else myb[i] = -1;
    }
    __syncthreads();
    for (int i = threadIdx.x; i < NBUCK; i += 256) {
        int c = bins[i];
        basel[i] = c ? atomicAdd(&gcursor[i], c) : 0;
    }
    __syncthreads();
#pragma unroll
    for (int i = 0; i < 8; i++)
        if (myb[i] >= 0) sorted[basel[myb[i]] + myr[i]] = myp[i];
}

// ---------------- Fused consumer: denom (LDS) + message (LDS) + bias + softmax ----------------
// One block per bucket. All accumulation in LDS; single coalesced output write.
__global__ __launch_bounds__(256) void fused_bucket_kernel(const int* __restrict__ base,
                                                           const int* __restrict__ sorted,
                                                           const unsigned short* __restrict__ s_src_b,
                                                           const unsigned short* __restrict__ s_tgt_b,
                                                           const unsigned short* __restrict__ projT,
                                                           const float* __restrict__ bias,
                                                           float* __restrict__ out) {
    __shared__ unsigned short stl[128 * 8];  // s_tgt slice, 2KB
    __shared__ float dnl[128 * 8];           // denom, 4KB
    __shared__ float outl[128 * 16];         // output acc, 8KB
    const int t = threadIdx.x;
    const int node0 = blockIdx.x * 128;
    for (int i = t; i < 1024; i += 256) {
        int node = node0 + (i >> 3);
        stl[i] = (node < NN) ? s_tgt_b[(size_t)node * 8 + (i & 7)] : (unsigned short)0;
        dnl[i] = 0.f;
    }
    for (int i = t; i < 2048; i += 256) outl[i] = 0.f;
    __syncthreads();
    const int e0 = base[blockIdx.x], e1 = base[blockIdx.x + 1];
    const int ne = e1 - e0;

    // Phase A: denominators
    for (int idx = t; idx < ne * 8; idx += 256) {
        int e = e0 + (idx >> 3), h = idx & 7;
        int p = sorted[e];
        int s = p >> 7, loc = p & 127;
        float v = bf16_to_f32(s_src_b[(size_t)s * 8 + h]) + bf16_to_f32(stl[loc * 8 + h]);
        v = v >= 0.f ? v : 0.2f * v;
        atomicAdd(&dnl[loc * 8 + h], expf(v));
    }
    __syncthreads();

    // Phase B: alpha-weighted head-mean message
    for (int idx = t; idx < ne * 16; idx += 256) {
        int e = e0 + (idx >> 4), f = idx & 15, h = f & 7;
        int p = sorted[e];
        int s = p >> 7, loc = p & 127;
        float v0 = bf16_to_f32(s_src_b[(size_t)s * 8 + h]) + bf16_to_f32(stl[loc * 8 + h]);
        v0 = v0 >= 0.f ? v0 : 0.2f * v0;
        float alpha = expf(v0) / (dnl[loc * 8 + h] + 1e-16f);
        uint4 v = *reinterpret_cast<const uint4*>(&projT[(size_t)s * 128 + f * 8]);
        float p0 = bf16_to_f32(v.x & 0xffffu), p1 = bf16_to_f32(v.x >> 16);
        float p2 = bf16_to_f32(v.y & 0xffffu), p3 = bf16_to_f32(v.y >> 16);
        float p4 = bf16_to_f32(v.z & 0xffffu), p5 = bf16_to_f32(v.z >> 16);
        float p6 = bf16_to_f32(v.w & 0xffffu), p7 = bf16_to_f32(v.w >> 16);
        float m = 0.f;
        m += __shfl(alpha, 0, 16) * p0;
        m += __shfl(alpha, 1, 16) * p1;
        m += __shfl(alpha, 2, 16) * p2;
        m += __shfl(alpha, 3, 16) * p3;
        m += __shfl(alpha, 4, 16) * p4;
        m += __shfl(alpha, 5, 16) * p5;
        m += __shfl(alpha, 6, 16) * p6;
        m += __shfl(alpha, 7, 16) * p7;
        atomicAdd(&outl[loc * 16 + f], m * 0.125f);
    }
    __syncthreads();

    // Epilogue: bias + softmax over 16 features, coalesced write
    for (int idx = t; idx < 2048; idx += 256) {
        int loc = idx >> 4, f = idx & 15;
        int node = node0 + loc;
        float v = outl[idx] + bias[f];
        float mx = v;
#pragma unroll
        for (int mm = 1; mm < 16; mm <<= 1) mx = fmaxf(mx, __shfl_xor(mx, mm, 16));
        float ex = expf(v - mx);
        float sum = ex;
#pragma unroll
        for (int mm = 1; mm < 16; mm <<= 1) sum += __shfl_xor(sum, mm, 16);
        if (node < NN) out[(size_t)node * 16 + f] = ex / sum;
    }
}

extern "C" void kernel_launch(void* const* d_in, const int* in_sizes, int n_in,
                              void* d_out, int out_size, void* d_ws, size_t ws_size,
                              hipStream_t stream) {
    const float* x     = (const float*)d_in[0];
    const int*   ei    = (const int*)d_in[1];
    const float* W     = (const float*)d_in[2];
    const float* a_src = (const float*)d_in[3];
    const float* a_tgt = (const float*)d_in[4];
    const float* bias  = (const float*)d_in[5];
    float* out = (float*)d_out;

    const int* src = ei;            // edge_index[0]
    const int* tgt = ei + NE;       // edge_index[1]

    char* ws = (char*)d_ws;
    size_t off = 0;
    auto alloc = [&](size_t bytes) {
        char* p = ws + off;
        off += (bytes + 255) & ~(size_t)255;
        return p;
    };
    unsigned short* projT   = (unsigned short*)alloc((size_t)NN * 128 * 2); // 25.6 MB bf16, f-major
    unsigned short* s_src_b = (unsigned short*)alloc((size_t)NN * 8 * 2);   // 1.6 MB
    unsigned short* s_tgt_b = (unsigned short*)alloc((size_t)NN * 8 * 2);   // 1.6 MB
    int*            counts  = (int*)alloc((size_t)NBUCK * 4);
    int*            bbase   = (int*)alloc((size_t)(NBUCK + 1) * 4);
    int*            gcursor = (int*)alloc((size_t)NBUCK * 4);
    int*            sorted  = (int*)alloc((size_t)NE * 4);                  // 6.4 MB

    hipMemsetAsync(counts, 0, (size_t)NBUCK * 4, stream);

    gemm_score_kernel<<<(NN + 63) / 64, 256, 0, stream>>>(x, W, a_src, a_tgt, projT, s_src_b, s_tgt_b);
    bucket_hist_kernel<<<(NE + 2047) / 2048, 256, 0, stream>>>(tgt, counts);
    bucket_scan_kernel<<<1, 1024, 0, stream>>>(counts, bbase, gcursor);
    bucket_scatter_kernel<<<(NE + 2047) / 2048, 256, 0, stream>>>(src, tgt, gcursor, sorted);
    fused_bucket_kernel<<<NBUCK, 256, 0, stream>>>(bbase, sorted, s_src_b, s_tgt_b, projT, bias, out);
}

// Round 17
// 292.971 us; speedup vs baseline: 1.5038x; 1.5038x over previous
//
#include <hip/hip_runtime.h>

#define NN 100000
#define NE 1600000
#define NBUCK 98   // ceil(NN/1024) source buckets; projT slice/bucket = 256 KB (L2-resident)
// IN_FEAT=128, N_HEADS=8, OUT_FEAT=16, H*F=128

static __device__ __forceinline__ unsigned short f32_to_bf16_rne(float x) {
    unsigned int u = __float_as_uint(x);
    u += 0x7fff + ((u >> 16) & 1);   // round-to-nearest-even
    return (unsigned short)(u >> 16);
}
static __device__ __forceinline__ float bf16_to_f32(unsigned int bits16) {
    return __uint_as_float(bits16 << 16);
}

// ---------------- Kernel 1: fused proj-GEMM + attention scores (round-13-measured) ----------------
__global__ __launch_bounds__(256) void gemm_score_kernel(const float* __restrict__ x,
                                                         const float* __restrict__ W,
                                                         const float* __restrict__ a_src,
                                                         const float* __restrict__ a_tgt,
                                                         unsigned short* __restrict__ projT,
                                                         unsigned short* __restrict__ s_src_b,
                                                         unsigned short* __restrict__ s_tgt_b) {
    __shared__ float sXT[32][68];   // k-major, padded
    __shared__ float sW[32][128];
    const int t = threadIdx.x;
    const int n0 = blockIdx.x * 64;
    const int c0 = (t & 31) * 4;    // head h=c0>>4, first feat f0=c0&15
    const int r0 = t >> 5;          // row group 0..7
    float acc[8][4];
#pragma unroll
    for (int i = 0; i < 8; i++)
#pragma unroll
        for (int j = 0; j < 4; j++) acc[i][j] = 0.f;

    for (int kt = 0; kt < 128; kt += 32) {
#pragma unroll
        for (int p = 0; p < 2; p++) {
            int idx = t + p * 256;
            int r = idx >> 3;
            int kk = idx & 7;
            float4 v = make_float4(0.f, 0.f, 0.f, 0.f);
            int n = n0 + r;
            if (n < NN) v = *reinterpret_cast<const float4*>(&x[(size_t)n * 128 + kt + kk * 4]);
            sXT[kk * 4 + 0][r] = v.x;
            sXT[kk * 4 + 1][r] = v.y;
            sXT[kk * 4 + 2][r] = v.z;
            sXT[kk * 4 + 3][r] = v.w;
        }
#pragma unroll
        for (int p = 0; p < 4; p++) {
            int idx = t + p * 256;
            int kr = idx >> 5;
            int c4 = idx & 31;
            float4 v = *reinterpret_cast<const float4*>(&W[(size_t)(kt + kr) * 128 + c4 * 4]);
            *reinterpret_cast<float4*>(&sW[kr][c4 * 4]) = v;
        }
        __syncthreads();
#pragma unroll
        for (int k = 0; k < 32; k++) {
            float4 xa = *reinterpret_cast<const float4*>(&sXT[k][r0 * 8]);
            float4 xb = *reinterpret_cast<const float4*>(&sXT[k][r0 * 8 + 4]);
            float4 wv = *reinterpret_cast<const float4*>(&sW[k][c0]);
            float xs[8] = {xa.x, xa.y, xa.z, xa.w, xb.x, xb.y, xb.z, xb.w};
#pragma unroll
            for (int i = 0; i < 8; i++) {
                acc[i][0] += xs[i] * wv.x;
                acc[i][1] += xs[i] * wv.y;
                acc[i][2] += xs[i] * wv.z;
                acc[i][3] += xs[i] * wv.w;
            }
        }
        __syncthreads();
    }
    const int h  = c0 >> 4;
    const int f0 = c0 & 15;
    const float aS0 = a_src[c0], aS1 = a_src[c0 + 1], aS2 = a_src[c0 + 2], aS3 = a_src[c0 + 3];
    const float aT0 = a_tgt[c0], aT1 = a_tgt[c0 + 1], aT2 = a_tgt[c0 + 2], aT3 = a_tgt[c0 + 3];
#pragma unroll
    for (int i = 0; i < 8; i++) {
        int n = n0 + r0 * 8 + i;
        if (n < NN) {
            unsigned short* pT = &projT[(size_t)n * 128];
#pragma unroll
            for (int j = 0; j < 4; j++) pT[(f0 + j) * 8 + h] = f32_to_bf16_rne(acc[i][j]);
            float ss = acc[i][0] * aS0 + acc[i][1] * aS1 + acc[i][2] * aS2 + acc[i][3] * aS3;
            float st = acc[i][0] * aT0 + acc[i][1] * aT1 + acc[i][2] * aT2 + acc[i][3] * aT3;
            ss += __shfl_xor(ss, 1);
            ss += __shfl_xor(ss, 2);
            st += __shfl_xor(st, 1);
            st += __shfl_xor(st, 2);
            if ((t & 3) == 0) {
                s_src_b[(size_t)n * 8 + h] = f32_to_bf16_rne(ss);
                s_tgt_b[(size_t)n * 8 + h] = f32_to_bf16_rne(st);
            }
        }
    }
}

// ---------------- Src-bucket counting-sort (98 buckets of 1024 source nodes) ----------------
// Consecutive sorted edges then read projT/s_src from a 256 KB slice -> L2-resident gathers.
__global__ __launch_bounds__(256) void bucket_hist_kernel(const int* __restrict__ src,
                                                          int* __restrict__ counts) {
    __shared__ int bins[NBUCK];
    for (int i = threadIdx.x; i < NBUCK; i += 256) bins[i] = 0;
    __syncthreads();
    int base = blockIdx.x * 2048;
#pragma unroll
    for (int i = 0; i < 8; i++) {
        int e = base + i * 256 + threadIdx.x;
        if (e < NE) atomicAdd(&bins[src[e] >> 10], 1);
    }
    __syncthreads();
    for (int i = threadIdx.x; i < NBUCK; i += 256)
        if (bins[i]) atomicAdd(&counts[i], bins[i]);
}

__global__ __launch_bounds__(128) void bucket_scan_kernel(const int* __restrict__ counts,
                                                          int* __restrict__ gcursor) {
    __shared__ int sc[128];
    int t = threadIdx.x;
    int v = (t < NBUCK) ? counts[t] : 0;
    sc[t] = v;
    __syncthreads();
    for (int off = 1; off < 128; off <<= 1) {
        int u = (t >= off) ? sc[t - off] : 0;
        __syncthreads();
        sc[t] += u;
        __syncthreads();
    }
    if (t < NBUCK) gcursor[t] = sc[t] - v;   // exclusive base
}

__global__ __launch_bounds__(256) void bucket_scatter_kernel(const int* __restrict__ src,
                                                             const int* __restrict__ tgt,
                                                             int* __restrict__ gcursor,
                                                             int2* __restrict__ sorted) {
    __shared__ int bins[NBUCK];
    __shared__ int basel[NBUCK];
    for (int i = threadIdx.x; i < NBUCK; i += 256) bins[i] = 0;
    __syncthreads();
    int blk = blockIdx.x * 2048;
    int myb[8], myr[8];
    int2 myp[8];
#pragma unroll
    for (int i = 0; i < 8; i++) {
        int e = blk + i * 256 + threadIdx.x;
        if (e < NE) {
            int s = src[e];
            int b = s >> 10;
            myb[i] = b;
            myr[i] = atomicAdd(&bins[b], 1);
            myp[i] = make_int2(s, tgt[e]);
        } else myb[i] = -1;
    }
    __syncthreads();
    for (int i = threadIdx.x; i < NBUCK; i += 256) {
        int c = bins[i];
        basel[i] = c ? atomicAdd(&gcursor[i], c) : 0;
    }
    __syncthreads();
#pragma unroll
    for (int i = 0; i < 8; i++)
        if (myb[i] >= 0) sorted[basel[myb[i]] + myr[i]] = myp[i];
}

// ---------------- Kernel 2: per-(edge,head) exp(leaky) -> denom + store ex (bf16) ----------------
// Consumes src-sorted edges: s_src reads near-sequential; s_tgt random (1.6 MB, L2-fit).
__global__ __launch_bounds__(256) void denom_kernel(const int2* __restrict__ sorted,
                                                    const unsigned short* __restrict__ s_src_b,
                                                    const unsigned short* __restrict__ s_tgt_b,
                                                    float* __restrict__ denom,
                                                    unsigned short* __restrict__ exb) {
    int gid = blockIdx.x * blockDim.x + threadIdx.x;
    int e = gid >> 3;
    if (e >= NE) return;
    int h = gid & 7;
    int2 p = sorted[e];
    float v = bf16_to_f32(s_src_b[(size_t)p.x * 8 + h]) + bf16_to_f32(s_tgt_b[(size_t)p.y * 8 + h]);
    v = v >= 0.f ? v : 0.2f * v;
    float ex = expf(v);
    exb[(size_t)e * 8 + h] = f32_to_bf16_rne(ex);
    atomicAdd(&denom[(size_t)p.y * 8 + h], ex);
}

// ---------------- Kernel 3: per-edge alpha, head-reduced message, scatter-add ----------------
// Src-sorted: the projT gather walks a 256 KB slice per bucket -> L2-resident reuse.
__global__ __launch_bounds__(256) void aggregate_kernel(const int2* __restrict__ sorted,
                                                        const float* __restrict__ denom,
                                                        const unsigned short* __restrict__ exb,
                                                        const unsigned short* __restrict__ projT,
                                                        float* __restrict__ out_acc) {
    int gid = blockIdx.x * blockDim.x + threadIdx.x;
    int e = gid >> 4;
    int lane = gid & 15;   // output feature f
    if (e >= NE) return;
    int2 p = sorted[e];
    int h = lane & 7;
    float ex = bf16_to_f32(exb[(size_t)e * 8 + h]);
    float alpha = ex / (denom[(size_t)p.y * 8 + h] + 1e-16f);
    uint4 v = *reinterpret_cast<const uint4*>(&projT[(size_t)p.x * 128 + lane * 8]);
    float p0 = bf16_to_f32(v.x & 0xffffu), p1 = bf16_to_f32(v.x >> 16);
    float p2 = bf16_to_f32(v.y & 0xffffu), p3 = bf16_to_f32(v.y >> 16);
    float p4 = bf16_to_f32(v.z & 0xffffu), p5 = bf16_to_f32(v.z >> 16);
    float p6 = bf16_to_f32(v.w & 0xffffu), p7 = bf16_to_f32(v.w >> 16);
    float m = 0.f;
    m += __shfl(alpha, 0, 16) * p0;
    m += __shfl(alpha, 1, 16) * p1;
    m += __shfl(alpha, 2, 16) * p2;
    m += __shfl(alpha, 3, 16) * p3;
    m += __shfl(alpha, 4, 16) * p4;
    m += __shfl(alpha, 5, 16) * p5;
    m += __shfl(alpha, 6, 16) * p6;
    m += __shfl(alpha, 7, 16) * p7;
    atomicAdd(&out_acc[(size_t)p.y * 16 + lane], m * 0.125f);
}

// ---------------- Kernel 4: bias + softmax over 16 features ----------------
__global__ __launch_bounds__(256) void softmax_kernel(const float* __restrict__ out_acc,
                                                      const float* __restrict__ bias,
                                                      float* __restrict__ out) {
    int gid = blockIdx.x * blockDim.x + threadIdx.x;
    int n = gid >> 4;
    int lane = gid & 15;
    if (n >= NN) return;
    float v = out_acc[(size_t)n * 16 + lane] + bias[lane];
    float mx = v;
#pragma unroll
    for (int m = 1; m < 16; m <<= 1) mx = fmaxf(mx, __shfl_xor(mx, m, 64));
    float ex = expf(v - mx);
    float sum = ex;
#pragma unroll
    for (int m = 1; m < 16; m <<= 1) sum += __shfl_xor(sum, m, 64);
    out[(size_t)n * 16 + lane] = ex / sum;
}

extern "C" void kernel_launch(void* const* d_in, const int* in_sizes, int n_in,
                              void* d_out, int out_size, void* d_ws, size_t ws_size,
                              hipStream_t stream) {
    const float* x     = (const float*)d_in[0];
    const int*   ei    = (const int*)d_in[1];
    const float* W     = (const float*)d_in[2];
    const float* a_src = (const float*)d_in[3];
    const float* a_tgt = (const float*)d_in[4];
    const float* bias  = (const float*)d_in[5];
    float* out = (float*)d_out;

    const int* src = ei;            // edge_index[0]
    const int* tgt = ei + NE;       // edge_index[1]

    char* ws = (char*)d_ws;
    size_t off = 0;
    auto alloc = [&](size_t bytes) {
        char* p = ws + off;
        off += (bytes + 255) & ~(size_t)255;
        return p;
    };
    unsigned short* projT   = (unsigned short*)alloc((size_t)NN * 128 * 2); // 25.6 MB bf16, f-major
    unsigned short* exb     = (unsigned short*)alloc((size_t)NE * 8 * 2);   // 25.6 MB bf16 ex[e][h]
    unsigned short* s_src_b = (unsigned short*)alloc((size_t)NN * 8 * 2);   // 1.6 MB
    unsigned short* s_tgt_b = (unsigned short*)alloc((size_t)NN * 8 * 2);   // 1.6 MB
    float*          denom   = (float*)alloc((size_t)NN * 8 * 4);            // 3.2 MB
    float*          out_acc = (float*)alloc((size_t)NN * 16 * 4);           // 6.4 MB
    int*            counts  = (int*)alloc((size_t)NBUCK * 4);
    int*            gcursor = (int*)alloc((size_t)NBUCK * 4);
    int2*           sorted  = (int2*)alloc((size_t)NE * 8);                 // 12.8 MB

    hipMemsetAsync(counts, 0, (size_t)NBUCK * 4, stream);
    hipMemsetAsync(denom, 0, (size_t)NN * 8 * 4, stream);
    hipMemsetAsync(out_acc, 0, (size_t)NN * 16 * 4, stream);

    gemm_score_kernel<<<(NN + 63) / 64, 256, 0, stream>>>(x, W, a_src, a_tgt, projT, s_src_b, s_tgt_b);
    bucket_hist_kernel<<<(NE + 2047) / 2048, 256, 0, stream>>>(src, counts);
    bucket_scan_kernel<<<1, 128, 0, stream>>>(counts, gcursor);
    bucket_scatter_kernel<<<(NE + 2047) / 2048, 256, 0, stream>>>(src, tgt, gcursor, sorted);
    denom_kernel<<<((size_t)NE * 8 + 255) / 256, 256, 0, stream>>>(sorted, s_src_b, s_tgt_b, denom, exb);
    aggregate_kernel<<<((size_t)NE * 16 + 255) / 256, 256, 0, stream>>>(sorted, denom, exb,
                                                                        projT, out_acc);
    softmax_kernel<<<(NN * 16 + 255) / 256, 256, 0, stream>>>(out_acc, bias, out);
}

// Round 18
// 242.697 us; speedup vs baseline: 1.8153x; 1.2071x over previous
//
#include <hip/hip_runtime.h>
#include <hip/hip_fp16.h>

#define NN 100000
#define NE 1600000
// IN_FEAT=128, N_HEADS=8, OUT_FEAT=16, H*F=128

static __device__ __forceinline__ unsigned short f32_to_bf16_rne(float x) {
    unsigned int u = __float_as_uint(x);
    u += 0x7fff + ((u >> 16) & 1);   // round-to-nearest-even
    return (unsigned short)(u >> 16);
}
static __device__ __forceinline__ float bf16_to_f32(unsigned int bits16) {
    return __uint_as_float(bits16 << 16);
}

// ---------------- Kernel 1: fused proj-GEMM + attention scores (round-13-measured) ----------------
__global__ __launch_bounds__(256) void gemm_score_kernel(const float* __restrict__ x,
                                                         const float* __restrict__ W,
                                                         const float* __restrict__ a_src,
                                                         const float* __restrict__ a_tgt,
                                                         unsigned short* __restrict__ projT,
                                                         unsigned short* __restrict__ s_src_b,
                                                         unsigned short* __restrict__ s_tgt_b) {
    __shared__ float sXT[32][68];   // k-major, padded
    __shared__ float sW[32][128];
    const int t = threadIdx.x;
    const int n0 = blockIdx.x * 64;
    const int c0 = (t & 31) * 4;    // head h=c0>>4, first feat f0=c0&15
    const int r0 = t >> 5;          // row group 0..7
    float acc[8][4];
#pragma unroll
    for (int i = 0; i < 8; i++)
#pragma unroll
        for (int j = 0; j < 4; j++) acc[i][j] = 0.f;

    for (int kt = 0; kt < 128; kt += 32) {
#pragma unroll
        for (int p = 0; p < 2; p++) {
            int idx = t + p * 256;
            int r = idx >> 3;
            int kk = idx & 7;
            float4 v = make_float4(0.f, 0.f, 0.f, 0.f);
            int n = n0 + r;
            if (n < NN) v = *reinterpret_cast<const float4*>(&x[(size_t)n * 128 + kt + kk * 4]);
            sXT[kk * 4 + 0][r] = v.x;
            sXT[kk * 4 + 1][r] = v.y;
            sXT[kk * 4 + 2][r] = v.z;
            sXT[kk * 4 + 3][r] = v.w;
        }
#pragma unroll
        for (int p = 0; p < 4; p++) {
            int idx = t + p * 256;
            int kr = idx >> 5;
            int c4 = idx & 31;
            float4 v = *reinterpret_cast<const float4*>(&W[(size_t)(kt + kr) * 128 + c4 * 4]);
            *reinterpret_cast<float4*>(&sW[kr][c4 * 4]) = v;
        }
        __syncthreads();
#pragma unroll
        for (int k = 0; k < 32; k++) {
            float4 xa = *reinterpret_cast<const float4*>(&sXT[k][r0 * 8]);
            float4 xb = *reinterpret_cast<const float4*>(&sXT[k][r0 * 8 + 4]);
            float4 wv = *reinterpret_cast<const float4*>(&sW[k][c0]);
            float xs[8] = {xa.x, xa.y, xa.z, xa.w, xb.x, xb.y, xb.z, xb.w};
#pragma unroll
            for (int i = 0; i < 8; i++) {
                acc[i][0] += xs[i] * wv.x;
                acc[i][1] += xs[i] * wv.y;
                acc[i][2] += xs[i] * wv.z;
                acc[i][3] += xs[i] * wv.w;
            }
        }
        __syncthreads();
    }
    const int h  = c0 >> 4;
    const int f0 = c0 & 15;
    const float aS0 = a_src[c0], aS1 = a_src[c0 + 1], aS2 = a_src[c0 + 2], aS3 = a_src[c0 + 3];
    const float aT0 = a_tgt[c0], aT1 = a_tgt[c0 + 1], aT2 = a_tgt[c0 + 2], aT3 = a_tgt[c0 + 3];
#pragma unroll
    for (int i = 0; i < 8; i++) {
        int n = n0 + r0 * 8 + i;
        if (n < NN) {
            unsigned short* pT = &projT[(size_t)n * 128];
#pragma unroll
            for (int j = 0; j < 4; j++) pT[(f0 + j) * 8 + h] = f32_to_bf16_rne(acc[i][j]);
            float ss = acc[i][0] * aS0 + acc[i][1] * aS1 + acc[i][2] * aS2 + acc[i][3] * aS3;
            float st = acc[i][0] * aT0 + acc[i][1] * aT1 + acc[i][2] * aT2 + acc[i][3] * aT3;
            ss += __shfl_xor(ss, 1);
            ss += __shfl_xor(ss, 2);
            st += __shfl_xor(st, 1);
            st += __shfl_xor(st, 2);
            if ((t & 3) == 0) {
                s_src_b[(size_t)n * 8 + h] = f32_to_bf16_rne(ss);
                s_tgt_b[(size_t)n * 8 + h] = f32_to_bf16_rne(st);
            }
        }
    }
}

// ---------------- Kernel 2: denom via packed-f16 HW atomics ----------------
// 4 lanes per edge; lane q handles heads (2q, 2q+1): u32 score reads, u32 exb write,
// ONE global_atomic_pk_add_f16 -> 6.4M atomic ops (was 12.8M f32).
__global__ __launch_bounds__(256) void denom_kernel(const int* __restrict__ src,
                                                    const int* __restrict__ tgt,
                                                    const unsigned short* __restrict__ s_src_b,
                                                    const unsigned short* __restrict__ s_tgt_b,
                                                    __half* __restrict__ denom_h,
                                                    unsigned short* __restrict__ exb) {
    int gid = blockIdx.x * blockDim.x + threadIdx.x;
    int e = gid >> 2;
    if (e >= NE) return;
    int h0 = (gid & 3) * 2;
    int s = src[e], t = tgt[e];
    unsigned int ssp = *reinterpret_cast<const unsigned int*>(&s_src_b[(size_t)s * 8 + h0]);
    unsigned int stp = *reinterpret_cast<const unsigned int*>(&s_tgt_b[(size_t)t * 8 + h0]);
    float v0 = bf16_to_f32(ssp & 0xffffu) + bf16_to_f32(stp & 0xffffu);
    float v1 = bf16_to_f32(ssp >> 16) + bf16_to_f32(stp >> 16);
    v0 = v0 >= 0.f ? v0 : 0.2f * v0;
    v1 = v1 >= 0.f ? v1 : 0.2f * v1;
    float ex0 = expf(v0), ex1 = expf(v1);
    unsigned int pk = (unsigned int)f32_to_bf16_rne(ex0) | ((unsigned int)f32_to_bf16_rne(ex1) << 16);
    *reinterpret_cast<unsigned int*>(&exb[(size_t)e * 8 + h0]) = pk;
    unsafeAtomicAdd(reinterpret_cast<__half2*>(&denom_h[(size_t)t * 8 + h0]),
                    __floats2half2_rn(ex0, ex1));
}

// ---------------- Kernel 3: aggregate via packed-f16 HW atomics ----------------
// 8 lanes per edge; lane j owns features (2j, 2j+1) and computes alpha for head j;
// 8 alphas shared via width-8 shuffle; ONE packed atomic -> 12.8M ops (was 25.6M).
__global__ __launch_bounds__(256) void aggregate_kernel(const int* __restrict__ src,
                                                        const int* __restrict__ tgt,
                                                        const __half* __restrict__ denom_h,
                                                        const unsigned short* __restrict__ exb,
                                                        const unsigned short* __restrict__ projT,
                                                        __half* __restrict__ out_h) {
    int gid = blockIdx.x * blockDim.x + threadIdx.x;
    int e = gid >> 3;
    if (e >= NE) return;
    int j = gid & 7;       // head j; features 2j, 2j+1
    int s = src[e], t = tgt[e];
    float ex = bf16_to_f32(exb[(size_t)e * 8 + j]);
    float dj = __half2float(denom_h[(size_t)t * 8 + j]);
    float alpha = ex / (dj + 1e-16f);
    // projT rows for features 2j and 2j+1 (8 heads each): 2x 16B loads
    uint4 va = *reinterpret_cast<const uint4*>(&projT[(size_t)s * 128 + (2 * j) * 8]);
    uint4 vb = *reinterpret_cast<const uint4*>(&projT[(size_t)s * 128 + (2 * j + 1) * 8]);
    float m0 = 0.f, m1 = 0.f;
#pragma unroll
    for (int k = 0; k < 8; k++) {
        float ak = __shfl(alpha, k, 8);
        unsigned int wa = (k & 1) ? ((&va.x)[k >> 1] >> 16) : ((&va.x)[k >> 1] & 0xffffu);
        unsigned int wb = (k & 1) ? ((&vb.x)[k >> 1] >> 16) : ((&vb.x)[k >> 1] & 0xffffu);
        m0 += ak * bf16_to_f32(wa);
        m1 += ak * bf16_to_f32(wb);
    }
    unsafeAtomicAdd(reinterpret_cast<__half2*>(&out_h[(size_t)t * 16 + 2 * j]),
                    __floats2half2_rn(m0 * 0.125f, m1 * 0.125f));
}

// ---------------- Kernel 4: bias + softmax over 16 features ----------------
__global__ __launch_bounds__(256) void softmax_kernel(const __half* __restrict__ out_h,
                                                      const float* __restrict__ bias,
                                                      float* __restrict__ out) {
    int gid = blockIdx.x * blockDim.x + threadIdx.x;
    int n = gid >> 4;
    int lane = gid & 15;
    if (n >= NN) return;
    float v = __half2float(out_h[(size_t)n * 16 + lane]) + bias[lane];
    float mx = v;
#pragma unroll
    for (int m = 1; m < 16; m <<= 1) mx = fmaxf(mx, __shfl_xor(mx, m, 64));
    float ex = expf(v - mx);
    float sum = ex;
#pragma unroll
    for (int m = 1; m < 16; m <<= 1) sum += __shfl_xor(sum, m, 64);
    out[(size_t)n * 16 + lane] = ex / sum;
}

extern "C" void kernel_launch(void* const* d_in, const int* in_sizes, int n_in,
                              void* d_out, int out_size, void* d_ws, size_t ws_size,
                              hipStream_t stream) {
    const float* x     = (const float*)d_in[0];
    const int*   ei    = (const int*)d_in[1];
    const float* W     = (const float*)d_in[2];
    const float* a_src = (const float*)d_in[3];
    const float* a_tgt = (const float*)d_in[4];
    const float* bias  = (const float*)d_in[5];
    float* out = (float*)d_out;

    const int* src = ei;            // edge_index[0]
    const int* tgt = ei + NE;       // edge_index[1]

    char* ws = (char*)d_ws;
    size_t off = 0;
    auto alloc = [&](size_t bytes) {
        char* p = ws + off;
        off += (bytes + 255) & ~(size_t)255;
        return p;
    };
    unsigned short* projT   = (unsigned short*)alloc((size_t)NN * 128 * 2); // 25.6 MB bf16, f-major
    unsigned short* exb     = (unsigned short*)alloc((size_t)NE * 8 * 2);   // 25.6 MB bf16 ex[e][h]
    unsigned short* s_src_b = (unsigned short*)alloc((size_t)NN * 8 * 2);   // 1.6 MB
    unsigned short* s_tgt_b = (unsigned short*)alloc((size_t)NN * 8 * 2);   // 1.6 MB
    __half*         denom_h = (__half*)alloc((size_t)NN * 8 * 2);           // 1.6 MB f16
    __half*         out_h   = (__half*)alloc((size_t)NN * 16 * 2);          // 3.2 MB f16

    // zero accumulators every call (f16 +0.0 is all-zero bits)
    hipMemsetAsync(denom_h, 0, (size_t)NN * 8 * 2, stream);
    hipMemsetAsync(out_h, 0, (size_t)NN * 16 * 2, stream);

    gemm_score_kernel<<<(NN + 63) / 64, 256, 0, stream>>>(x, W, a_src, a_tgt, projT, s_src_b, s_tgt_b);
    denom_kernel<<<((size_t)NE * 4 + 255) / 256, 256, 0, stream>>>(src, tgt, s_src_b, s_tgt_b,
                                                                   denom_h, exb);
    aggregate_kernel<<<((size_t)NE * 8 + 255) / 256, 256, 0, stream>>>(src, tgt, denom_h, exb,
                                                                       projT, out_h);
    softmax_kernel<<<(NN * 16 + 255) / 256, 256, 0, stream>>>(out_h, bias, out);
}